// Round 1
// 687.375 us; speedup vs baseline: 1.0562x; 1.0562x over previous
//
#include <hip/hip_runtime.h>
#include <stdint.h>

// SmallMLP_INR: fused 6-layer MLP (2->256->256x4->1, ReLU) over 524288 points.
// Split-bf16 MFMA (x = hi + lo, truncate split): Y = Xh*Wh + Xh*Wl + Xl*Wh in fp32.
// THIS VERSION: operand-swapped MFMA — compute Yt = Wt * Xt (weights as A-frag,
// activations as B-frag). A/B fragment layouts are mutual transposes, so the
// weight packing AND the LDS activation-read pattern are unchanged; but the
// accumulator now holds 4 CONSECUTIVE output features per thread, so the
// epilogue writes 8B ds_write_b64 (bank-balanced under the XOR swizzle) instead
// of 128 scattered ds_write_b16 (4-way conflicts). Layer 1 restructured the
// same way. s_setprio(1) around the MFMA cluster (2 blocks/CU phase diversity).

#define WIDTH 256
#define MT 64

typedef short short8 __attribute__((ext_vector_type(8)));
typedef float float4v __attribute__((ext_vector_type(4)));
typedef unsigned int uint2v __attribute__((ext_vector_type(2)));

// truncate-split f32 -> bf16 hi + bf16 lo (lo also truncated; total ~16-17 bits)
__device__ __forceinline__ void split_bf(float f, unsigned short &hi, unsigned short &lo) {
    union { float f; uint32_t u; } a; a.f = f;
    hi = (unsigned short)(a.u >> 16);
    union { uint32_t u; float f; } h; h.u = a.u & 0xffff0000u;
    union { float f; uint32_t u; } d; d.f = f - h.f;   // exact (Sterbenz)
    lo = (unsigned short)(d.u >> 16);
}

__device__ __forceinline__ float bf2f(unsigned short h) {
    union { uint32_t u; float f; } a; a.u = ((uint32_t)h) << 16; return a.f;
}

// pack hi(bf16) of two f32 into one u32: low ushort = hi(a), high ushort = hi(b)
__device__ __forceinline__ uint32_t pack_hi(float a, float b) {
    union { float f; uint32_t u; } ua, ub; ua.f = a; ub.f = b;
    return (ub.u & 0xffff0000u) | (ua.u >> 16);
}
// pack lo(bf16) of two f32 into one u32
__device__ __forceinline__ uint32_t pack_lo(float a, float b) {
    union { float f; uint32_t u; } ua, ub; ua.f = a; ub.f = b;
    union { uint32_t u; float f; } ha, hb; ha.u = ua.u & 0xffff0000u; hb.u = ub.u & 0xffff0000u;
    union { float f; uint32_t u; } da, db; da.f = a - ha.f; db.f = b - hb.f;
    return (db.u & 0xffff0000u) | (da.u >> 16);
}

// LDS activation addressing: X[m][n], row stride 256 ushorts, 16B-chunk index
// XOR-swizzled by (m&7) -> conflict-free MFMA B-frag reads without padding.
__device__ __forceinline__ int xaddr(int m, int n) {
    int c = n >> 3;
    return m * 256 + (((c ^ (m & 7)) << 3) | (n & 7));
}

// Pack W2..W5 (256x256, row-major [k][n]) into MFMA fragment order:
// [l][ct(16)][ks(8)][lane(64)][j(8)], n = 16*ct + (lane&15), k = 32*ks + 8*(lane>>4) + j.
// Identical layout serves as the A-frag of Wt (A and B layouts are transposes).
__global__ void prep_weights(const float* __restrict__ W2, const float* __restrict__ W3,
                             const float* __restrict__ W4, const float* __restrict__ W5,
                             unsigned short* __restrict__ whi, unsigned short* __restrict__ wlo) {
    int tid = blockIdx.x * 256 + threadIdx.x;   // 4*65536 total
    int l = tid >> 16;
    int e = tid & 65535;
    int j = e & 7;
    int lane = (e >> 3) & 63;
    int ks = (e >> 9) & 7;
    int ct = (e >> 12) & 15;
    int n = ct * 16 + (lane & 15);
    int k = ks * 32 + (lane >> 4) * 8 + j;
    const float* W = (l == 0) ? W2 : (l == 1) ? W3 : (l == 2) ? W4 : W5;
    float w = W[k * 256 + n];
    unsigned short hi, lo;
    split_bf(w, hi, lo);
    whi[tid] = hi;
    wlo[tid] = lo;
}

__global__ __launch_bounds__(256, 2) void mlp_fused(
    const float* __restrict__ coords,
    const float* __restrict__ W1, const float* __restrict__ b1,
    const float* __restrict__ b2, const float* __restrict__ b3,
    const float* __restrict__ b4, const float* __restrict__ b5,
    const float* __restrict__ W6, const float* __restrict__ b6,
    const unsigned short* __restrict__ whi, const unsigned short* __restrict__ wlo,
    float* __restrict__ out)
{
    __shared__ unsigned short Xhi[64 * 256];   // 32 KB
    __shared__ unsigned short Xlo[64 * 256];   // 32 KB  (total exactly 64 KB)

    const int tid = threadIdx.x;
    const int m0 = blockIdx.x * MT;

    // ---- layer 1: 2 -> 256 (VALU). Thread owns 4 consecutive cols nq..nq+3,
    //      wave w handles m = 4*i + w  -> b64 LDS writes, bank-balanced. ----
    {
        const int lw = tid & 63;
        const int mg = tid >> 6;
        const int nq = lw * 4;
        const float4v w0 = *(const float4v*)(W1 + nq);          // W1[0][nq..nq+3]
        const float4v w1 = *(const float4v*)(W1 + WIDTH + nq);  // W1[1][nq..nq+3]
        const float4v bb = *(const float4v*)(b1 + nq);
        for (int i = 0; i < 16; ++i) {
            const int m = 4 * i + mg;
            const float c0 = coords[(m0 + m) * 2];       // wave-uniform address
            const float c1 = coords[(m0 + m) * 2 + 1];
            float v[4];
            #pragma unroll
            for (int j = 0; j < 4; ++j)
                v[j] = fmaxf(fmaf(c0, w0[j], fmaf(c1, w1[j], bb[j])), 0.0f);
            const int a = xaddr(m, nq);                  // nq&7 in {0,4}: stays in chunk
            *(uint2v*)(Xhi + a) = (uint2v){pack_hi(v[0], v[1]), pack_hi(v[2], v[3])};
            *(uint2v*)(Xlo + a) = (uint2v){pack_lo(v[0], v[1]), pack_lo(v[2], v[3])};
        }
    }
    __syncthreads();

    const int wv   = tid >> 6;     // wave 0..3 owns output features [64*wv, 64*wv+64)
    const int lane = tid & 63;
    const int quad = lane >> 4;
    const int l16  = lane & 15;

    // ---- layers 2..5: 256 -> 256 via 16x16x32 bf16 MFMA, operand-swapped ----
    // D[f][p] = sum_k Wt[f][k] * Xt[k][p]; A = Wt frag (global, packed),
    // B = Xt frag == X[16*pt+l16][32*ks+8*quad + 0..7] (identical read as before).
    for (int l = 0; l < 4; ++l) {
        const float* bias = (l == 0) ? b2 : (l == 1) ? b3 : (l == 2) ? b4 : b5;

        float4v acc[4][4];   // acc[ft][pt]
        #pragma unroll
        for (int ft = 0; ft < 4; ++ft)
            #pragma unroll
            for (int pt = 0; pt < 4; ++pt)
                acc[ft][pt] = (float4v){0.f, 0.f, 0.f, 0.f};

        #pragma unroll 2
        for (int ks = 0; ks < 8; ++ks) {
            short8 xh[4], xl[4], wh[4], wl[4];
            #pragma unroll
            for (int pt = 0; pt < 4; ++pt) {
                // B-frag: B[k][p], p = lane&15, k = 32*ks + 8*quad + j
                int off = xaddr(16 * pt + l16, 32 * ks + 8 * quad);
                xh[pt] = *(const short8*)(Xhi + off);
                xl[pt] = *(const short8*)(Xlo + off);
            }
            #pragma unroll
            for (int ft = 0; ft < 4; ++ft) {
                // A-frag: Wt[f][k], f = 16*(4*wv+ft) + (lane&15), k = 32*ks + 8*(lane>>4) + j
                int idx = ((((l * 16) + (4 * wv + ft)) * 8 + ks) * 64 + lane) * 8;
                wh[ft] = *(const short8*)(whi + idx);
                wl[ft] = *(const short8*)(wlo + idx);
            }
            __builtin_amdgcn_s_setprio(1);
            #pragma unroll
            for (int ft = 0; ft < 4; ++ft)
                #pragma unroll
                for (int pt = 0; pt < 4; ++pt) {
                    acc[ft][pt] = __builtin_amdgcn_mfma_f32_16x16x32_bf16(wh[ft], xh[pt], acc[ft][pt], 0, 0, 0);
                    acc[ft][pt] = __builtin_amdgcn_mfma_f32_16x16x32_bf16(wh[ft], xl[pt], acc[ft][pt], 0, 0, 0);
                    acc[ft][pt] = __builtin_amdgcn_mfma_f32_16x16x32_bf16(wl[ft], xh[pt], acc[ft][pt], 0, 0, 0);
                }
            __builtin_amdgcn_s_setprio(0);
        }
        __syncthreads();   // all waves done reading X before overwrite

        // epilogue: D row = 4*quad + r = feature offset (4 CONSECUTIVE features
        // per thread at point m = 16*pt + l16) -> bias+ReLU+split, b64 writes.
        #pragma unroll
        for (int ft = 0; ft < 4; ++ft) {
            const int nb = 64 * wv + 16 * ft + 4 * quad;       // nb&7 in {0,4}
            const float4v bb = *(const float4v*)(bias + nb);
            #pragma unroll
            for (int pt = 0; pt < 4; ++pt) {
                const int m = 16 * pt + l16;
                float v[4];
                #pragma unroll
                for (int r = 0; r < 4; ++r)
                    v[r] = fmaxf(acc[ft][pt][r] + bb[r], 0.0f);
                const int a = xaddr(m, nb);
                *(uint2v*)(Xhi + a) = (uint2v){pack_hi(v[0], v[1]), pack_hi(v[2], v[3])};
                *(uint2v*)(Xlo + a) = (uint2v){pack_lo(v[0], v[1]), pack_lo(v[2], v[3])};
            }
        }
        __syncthreads();
    }

    // ---- layer 6: 256 -> 1 (VALU). 4 threads per point, shuffle-reduce. ----
    {
        const int m = tid >> 2;
        const int cq = tid & 3;
        float s = 0.0f;
        #pragma unroll
        for (int g = 0; g < 8; ++g) {
            int nb = cq * 64 + g * 8;
            int a = xaddr(m, nb);
            const short8 hv = *(const short8*)(Xhi + a);
            const short8 lv = *(const short8*)(Xlo + a);
            const float* wp = W6 + nb;
            #pragma unroll
            for (int j = 0; j < 8; ++j) {
                float x = bf2f((unsigned short)hv[j]) + bf2f((unsigned short)lv[j]);
                s = fmaf(x, wp[j], s);
            }
        }
        s += __shfl_xor(s, 1);
        s += __shfl_xor(s, 2);
        if (cq == 0) out[m0 + m] = s + b6[0];
    }
}

extern "C" void kernel_launch(void* const* d_in, const int* in_sizes, int n_in,
                              void* d_out, int out_size, void* d_ws, size_t ws_size,
                              hipStream_t stream) {
    const float* coords = (const float*)d_in[0];
    const float* W1 = (const float*)d_in[1];
    const float* b1 = (const float*)d_in[2];
    const float* W2 = (const float*)d_in[3];
    const float* b2 = (const float*)d_in[4];
    const float* W3 = (const float*)d_in[5];
    const float* b3 = (const float*)d_in[6];
    const float* W4 = (const float*)d_in[7];
    const float* b4 = (const float*)d_in[8];
    const float* W5 = (const float*)d_in[9];
    const float* b5 = (const float*)d_in[10];
    const float* W6 = (const float*)d_in[11];
    const float* b6 = (const float*)d_in[12];
    float* out = (float*)d_out;

    unsigned short* whi = (unsigned short*)d_ws;        // 4*65536 ushorts = 512 KB
    unsigned short* wlo = whi + 4 * 65536;              // 512 KB (ws total 1 MB)

    prep_weights<<<1024, 256, 0, stream>>>(W2, W3, W4, W5, whi, wlo);

    const int nblocks = out_size / MT;                  // 524288 / 64 = 8192
    mlp_fused<<<nblocks, 256, 0, stream>>>(coords, W1, b1, b2, b3, b4, b5,
                                           W6, b6, whi, wlo, out);
}